// Round 3
// baseline (100.690 us; speedup 1.0000x reference)
//
#include <hip/hip_runtime.h>
#include <hip/hip_cooperative_groups.h>

namespace cg = cooperative_groups;

// loss = (N*S - ||colsum||^2) / (sqrt(max_i sq_i) * N*(N-1)/2)
// where S = sum of all x^2, colsum[d] = sum_i x[i][d], sq_i = row squared norm.
// Derivation: sum_{i<j} (sq_i + sq_j - 2 x_i.x_j) = N*S - ||colsum||^2.
//
// SINGLE cooperative kernel (256 blocks x 512 thr), one grid sync:
//   phase1: 8 waves/block, wave handles 4 rows with register accumulation
//           (col[8] per lane), one pair of conflict-free ds_write_b128 per
//           lane into a per-wave LDS region (no LDS atomics), cross-wave
//           reduce -> per-block colsum/S/max partials in ws.
//           Block 0 zeroes the 4 finisher slots; the grid sync's device-scope
//           fence orders this before phase2's atomics (solves counter init
//           under graph replay with poisoned ws).
//   grid.sync()
//   phase2: blocks 0..63; block j reduces cols [8j,8j+8) over the 256
//           partials (512 thr: each sums 4 partials) -> q partial; 4-wide
//           slice of S/max; device-scope atomic accumulate +
//           last-block-done finisher emits the scalar.
// Rationale: fill (43.5us) + pass1 HBM floor (~2.7us) are fixed; residual is
// graph-node dispatch overhead -> cut one kernel node.

#define NROWS 8192
#define NCOLS 512
#define NB1   256                 // grid size
#define NB2   64                  // blocks participating in phase2
#define PS    (NB1 * NCOLS)       // ws: S partials [NB1]
#define PM    (PS + NB1)          // ws: max partials [NB1]
#define PACC  (PM + NB1)          // ws: q_acc, s_acc, m_acc(uint), counter(uint)

__global__ __launch_bounds__(512) void ndl_fused(const float* __restrict__ x,
                                                 float* __restrict__ ws,
                                                 float* __restrict__ out) {
    __shared__ float wcol[8][NCOLS];   // 16 KB: per-wave column partials
    __shared__ float s_part[8];
    __shared__ float m_part[8];
    __shared__ float wred[8 * 8];      // phase2: [wave][col']
    const int t    = threadIdx.x;
    const int lane = t & 63;
    const int wave = t >> 6;

    // finisher slots (zeroed every launch; ordered by grid sync below)
    if (blockIdx.x == 0 && t < 4) ws[PACC + t] = 0.f;

    // ---- phase 1: per-block partials ----
    // wave handles 4 consecutive rows; lane l covers columns 8l..8l+7
    const int row0 = blockIdx.x * 32 + wave * 4;
    const float4* xv = (const float4*)x;  // row stride = 128 float4

    float col[8] = {0.f, 0.f, 0.f, 0.f, 0.f, 0.f, 0.f, 0.f};
    float sp = 0.f;
    float maxsq = 0.f;

    #pragma unroll
    for (int r = 0; r < 4; ++r) {
        const int row = row0 + r;
        float4 a = xv[(size_t)row * 128 + lane * 2];
        float4 b = xv[(size_t)row * 128 + lane * 2 + 1];
        col[0] += a.x; col[1] += a.y; col[2] += a.z; col[3] += a.w;
        col[4] += b.x; col[5] += b.y; col[6] += b.z; col[7] += b.w;
        float rsq = a.x*a.x + a.y*a.y + a.z*a.z + a.w*a.w
                  + b.x*b.x + b.y*b.y + b.z*b.z + b.w*b.w;
        sp += rsq;
        #pragma unroll
        for (int off = 1; off < 64; off <<= 1)
            rsq += __shfl_xor(rsq, off, 64);
        maxsq = fmaxf(maxsq, rsq);
    }

    // one pair of conflict-free 16B LDS writes per lane (no atomics)
    float4* dst = (float4*)&wcol[wave][lane * 8];
    dst[0] = make_float4(col[0], col[1], col[2], col[3]);
    dst[1] = make_float4(col[4], col[5], col[6], col[7]);

    #pragma unroll
    for (int off = 1; off < 64; off <<= 1)
        sp += __shfl_xor(sp, off, 64);
    if (lane == 0) { s_part[wave] = sp; m_part[wave] = maxsq; }
    __syncthreads();

    // cross-wave reduce: thread t owns column t (conflict-free)
    float cs = 0.f;
    #pragma unroll
    for (int w = 0; w < 8; ++w)
        cs += wcol[w][t];
    ws[(size_t)blockIdx.x * NCOLS + t] = cs;

    if (t == 0) {
        float s = 0.f, m = 0.f;
        #pragma unroll
        for (int k = 0; k < 8; ++k) {
            s += s_part[k];
            m  = fmaxf(m, m_part[k]);
        }
        ws[PS + blockIdx.x] = s;
        ws[PM + blockIdx.x] = m;
    }

    // ---- grid-wide barrier (device-scope fence: partials + PACC visible) ----
    cg::this_grid().sync();

    // ---- phase 2: blocks 0..63 reduce; atomic finisher emits scalar ----
    if (blockIdx.x >= NB2) return;

    const int j = blockIdx.x;
    const int c = j * 8 + (t & 7);
    const int i = t >> 3;              // 0..63; each sums 4 block-partials

    const float* p = ws + (size_t)(i * 4) * NCOLS + c;
    float acc = 0.f;
    #pragma unroll
    for (int k = 0; k < 4; ++k)
        acc += p[(size_t)k * NCOLS];

    // sum over the 8 i-values within this wave (lane bits 3,4,5)
    acc += __shfl_xor(acc, 8, 64);
    acc += __shfl_xor(acc, 16, 64);
    acc += __shfl_xor(acc, 32, 64);
    if (lane < 8) wred[wave * 8 + lane] = acc;
    __syncthreads();

    if (t < 8) {
        float csum = 0.f;
        #pragma unroll
        for (int w = 0; w < 8; ++w)
            csum += wred[w * 8 + t];
        float q = csum * csum;
        // sum the 8 squares (threads 0..7, same wave)
        q += __shfl_xor(q, 1, 64);
        q += __shfl_xor(q, 2, 64);
        q += __shfl_xor(q, 4, 64);
        if (t == 0) {
            float s = 0.f, m = 0.f;
            #pragma unroll
            for (int k = 0; k < 4; ++k) {
                s += ws[PS + j * 4 + k];
                m  = fmaxf(m, ws[PM + j * 4 + k]);
            }
            atomicAdd(&ws[PACC + 0], q);
            atomicAdd(&ws[PACC + 1], s);
            atomicMax((unsigned int*)&ws[PACC + 2], __float_as_uint(m)); // all >= 0
            __threadfence();
            unsigned int old = atomicAdd((unsigned int*)&ws[PACC + 3], 1u);
            if (old == NB2 - 1) {
                __threadfence();
                // read via atomic RMW -> coherent point (cross-XCD safe)
                float qv = atomicAdd(&ws[PACC + 0], 0.f);
                float sv = atomicAdd(&ws[PACC + 1], 0.f);
                float mv = __uint_as_float(
                    atomicMax((unsigned int*)&ws[PACC + 2], 0u));
                double numer = (double)NROWS * (double)sv - (double)qv;
                double count = (double)NROWS * ((double)NROWS - 1.0) * 0.5;
                out[0] = (float)(numer / (sqrt((double)mv) * count));
            }
        }
    }
}

extern "C" void kernel_launch(void* const* d_in, const int* in_sizes, int n_in,
                              void* d_out, int out_size, void* d_ws, size_t ws_size,
                              hipStream_t stream) {
    const float* x = (const float*)d_in[0];
    float* out = (float*)d_out;
    float* ws  = (float*)d_ws;

    void* args[] = {(void*)&x, (void*)&ws, (void*)&out};
    hipLaunchCooperativeKernel((void*)ndl_fused, dim3(NB1), dim3(512),
                               args, 0, stream);
}